// Round 1
// baseline (1319.071 us; speedup 1.0000x reference)
//
#include <hip/hip_runtime.h>
#include <hip/hip_bf16.h>

#define T_SEQ 2048
#define DMODEL 1024
#define NH 16
#define HD 64

// ======================================================================
// GEMM: C[m,n] = sum_k A[m,k] * B[n,k]   (A: MxK row-major, B: NxK row-major)
// AMODE 0: A plain row-major.  AMODE 1: A gathered from (B,H,T,hd) layout.
// CMODE 0: C plain row-major.  CMODE 1: C scattered to (B,H,T,hd) layout.
// BM=BN=128, BK=16, 256 threads, 8x8 micro-tile (rows ty*4+i / 64+ty*4+i,
// cols tx*4+j / 64+tx*4+j so ds_read_b128 lanes are contiguous -> ~2-way max).
// ======================================================================
template<int AMODE, int CMODE>
__global__ __launch_bounds__(256)
void gemm_nt_kernel(const float* __restrict__ A, const float* __restrict__ B,
                    float* __restrict__ C, int M, int N, int K) {
  __shared__ float As[16][132];  // [BK][BM+4] transposed tile, 132*4B row = 16B-aligned
  __shared__ float Bs[16][132];
  const int tid = threadIdx.x;
  const int ty = tid >> 4, tx = tid & 15;
  const int m0 = blockIdx.y * 128, n0 = blockIdx.x * 128;

  float acc[8][8];
  #pragma unroll
  for (int i = 0; i < 8; ++i)
    #pragma unroll
    for (int j = 0; j < 8; ++j) acc[i][j] = 0.f;

  for (int k0 = 0; k0 < K; k0 += 16) {
    // ---- stage A,B tiles (transposed) ----
    #pragma unroll
    for (int half = 0; half < 2; ++half) {
      const int f  = tid + half * 256;   // 512 float4s per tile
      const int r  = f >> 2;             // 0..127
      const int c4 = (f & 3) * 4;        // 0,4,8,12
      const int k  = k0 + c4;
      float4 av, bv;
      {
        const int m = m0 + r;
        int aidx;
        if (AMODE == 0) aidx = m * K + k;
        else            aidx = ((m >> 11) * NH + (k >> 6)) * (T_SEQ * HD)
                               + (m & (T_SEQ - 1)) * HD + (k & (HD - 1));
        av = *(const float4*)(A + aidx);
      }
      {
        const int n = n0 + r;
        bv = *(const float4*)(B + n * K + k);
      }
      As[c4 + 0][r] = av.x; As[c4 + 1][r] = av.y; As[c4 + 2][r] = av.z; As[c4 + 3][r] = av.w;
      Bs[c4 + 0][r] = bv.x; Bs[c4 + 1][r] = bv.y; Bs[c4 + 2][r] = bv.z; Bs[c4 + 3][r] = bv.w;
    }
    __syncthreads();

    // ---- micro-GEMM ----
    #pragma unroll
    for (int kk = 0; kk < 16; ++kk) {
      const float4 a0 = *(const float4*)&As[kk][ty * 4];
      const float4 a1 = *(const float4*)&As[kk][64 + ty * 4];
      const float4 b0 = *(const float4*)&Bs[kk][tx * 4];
      const float4 b1 = *(const float4*)&Bs[kk][64 + tx * 4];
      const float a[8] = {a0.x, a0.y, a0.z, a0.w, a1.x, a1.y, a1.z, a1.w};
      const float b[8] = {b0.x, b0.y, b0.z, b0.w, b1.x, b1.y, b1.z, b1.w};
      #pragma unroll
      for (int i = 0; i < 8; ++i)
        #pragma unroll
        for (int j = 0; j < 8; ++j)
          acc[i][j] += a[i] * b[j];
    }
    __syncthreads();
  }

  // ---- epilogue ----
  #pragma unroll
  for (int i = 0; i < 8; ++i) {
    const int m = m0 + ((i < 4) ? (ty * 4 + i) : (64 + ty * 4 + (i - 4)));
    #pragma unroll
    for (int jh = 0; jh < 2; ++jh) {
      const int n = n0 + jh * 64 + tx * 4;
      const int j = jh * 4;
      const float4 v = make_float4(acc[i][j], acc[i][j + 1], acc[i][j + 2], acc[i][j + 3]);
      int cidx;
      if (CMODE == 0) cidx = m * N + n;
      else            cidx = ((m >> 11) * NH + (n >> 6)) * (T_SEQ * HD)
                             + (m & (T_SEQ - 1)) * HD + (n & (HD - 1));
      *(float4*)(C + cidx) = v;
    }
  }
}

// ======================================================================
// RoPE (interleaved pairs) applied in-place to Q and K in (B,H,T,hd) layout.
// One thread per (row, pair).  freqs_cis: (T, 32, 2) = (cos, sin).
// ======================================================================
__global__ __launch_bounds__(256)
void rope_kernel(float* __restrict__ Q, float* __restrict__ Kp,
                 const float* __restrict__ fc) {
  const int idx = blockIdx.x * 256 + threadIdx.x;  // B*NH*T*32 threads
  const int i   = idx & 31;
  const int row = idx >> 5;                        // (b*NH + h)*T + t
  const int t   = row & (T_SEQ - 1);
  const int a   = row * HD + 2 * i;
  const float c = fc[t * 64 + 2 * i];
  const float s = fc[t * 64 + 2 * i + 1];
  float2 q = *(float2*)(Q + a);
  float2 k = *(float2*)(Kp + a);
  float2 qo, ko;
  qo.x = q.x * c - q.y * s;  qo.y = q.x * s + q.y * c;
  ko.x = k.x * c - k.y * s;  ko.y = k.x * s + k.y * c;
  *(float2*)(Q + a)  = qo;
  *(float2*)(Kp + a) = ko;
}

// ======================================================================
// Flash-style causal attention, fp32.  One block = one (b,h) x 64-row Q tile.
// 256 threads as 16x16; thread (ty,tx) owns S/O rows ty*4+i, cols tx*4+j.
// K stored transposed in LDS (Kt[d][k]) so both gemms read contiguous b128.
// Online softmax with 16-lane __shfl_xor row reductions.
// ======================================================================
__global__ __launch_bounds__(256)
void attn_kernel(const float* __restrict__ Q, const float* __restrict__ K,
                 const float* __restrict__ V, float* __restrict__ O) {
  __shared__ float Qs[64][68];
  __shared__ float Kt[64][68];   // Kt[d][k]
  __shared__ float Vs[64][68];   // Vs[k][d]
  __shared__ float Ps[64][68];   // P tile
  const int tid = threadIdx.x;
  const int ty = tid >> 4, tx = tid & 15;
  const int qt = blockIdx.x;
  const int bh = blockIdx.y;
  const int base = bh * (T_SEQ * HD);
  const int q0 = qt * 64;

  // load + pre-scale Q tile
  #pragma unroll
  for (int it = 0; it < 4; ++it) {
    const int f = tid + it * 256;
    const int r = f >> 4, c = (f & 15) * 4;
    float4 v = *(const float4*)(Q + base + (q0 + r) * HD + c);
    v.x *= 0.125f; v.y *= 0.125f; v.z *= 0.125f; v.w *= 0.125f;
    *(float4*)&Qs[r][c] = v;
  }

  float o[4][4];
  float mrow[4], lrow[4];
  #pragma unroll
  for (int i = 0; i < 4; ++i) {
    mrow[i] = -3.0e38f; lrow[i] = 0.f;
    #pragma unroll
    for (int j = 0; j < 4; ++j) o[i][j] = 0.f;
  }

  for (int kt = 0; kt <= qt; ++kt) {
    const int k0 = kt * 64;
    __syncthreads();  // previous iteration's PV reads done before overwrite
    #pragma unroll
    for (int it = 0; it < 4; ++it) {
      const int f = tid + it * 256;
      const int r = f >> 4, c = (f & 15) * 4;
      const float4 kv = *(const float4*)(K + base + (k0 + r) * HD + c);
      Kt[c + 0][r] = kv.x; Kt[c + 1][r] = kv.y; Kt[c + 2][r] = kv.z; Kt[c + 3][r] = kv.w;
      const float4 vv = *(const float4*)(V + base + (k0 + r) * HD + c);
      *(float4*)&Vs[r][c] = vv;
    }
    __syncthreads();

    // ---- S = (Q*scale) K^T ----
    float s[4][4];
    #pragma unroll
    for (int i = 0; i < 4; ++i)
      #pragma unroll
      for (int j = 0; j < 4; ++j) s[i][j] = 0.f;

    #pragma unroll
    for (int d0 = 0; d0 < 64; d0 += 4) {
      float qv[4][4], kv[4][4];
      #pragma unroll
      for (int i = 0; i < 4; ++i) {
        const float4 t4 = *(const float4*)&Qs[ty * 4 + i][d0];
        qv[i][0] = t4.x; qv[i][1] = t4.y; qv[i][2] = t4.z; qv[i][3] = t4.w;
      }
      #pragma unroll
      for (int l = 0; l < 4; ++l) {
        const float4 t4 = *(const float4*)&Kt[d0 + l][tx * 4];
        kv[l][0] = t4.x; kv[l][1] = t4.y; kv[l][2] = t4.z; kv[l][3] = t4.w;
      }
      #pragma unroll
      for (int i = 0; i < 4; ++i)
        #pragma unroll
        for (int j = 0; j < 4; ++j)
          s[i][j] += qv[i][0] * kv[0][j] + qv[i][1] * kv[1][j]
                   + qv[i][2] * kv[2][j] + qv[i][3] * kv[3][j];
    }

    // ---- causal mask on diagonal tile ----
    if (kt == qt) {
      #pragma unroll
      for (int i = 0; i < 4; ++i)
        #pragma unroll
        for (int j = 0; j < 4; ++j)
          if (tx * 4 + j > ty * 4 + i) s[i][j] = -1.0e9f;
    }

    // ---- online softmax (row reductions over 16 tx lanes) ----
    float tmax[4];
    #pragma unroll
    for (int i = 0; i < 4; ++i)
      tmax[i] = fmaxf(fmaxf(s[i][0], s[i][1]), fmaxf(s[i][2], s[i][3]));
    #pragma unroll
    for (int off = 1; off < 16; off <<= 1)
      #pragma unroll
      for (int i = 0; i < 4; ++i)
        tmax[i] = fmaxf(tmax[i], __shfl_xor(tmax[i], off));

    float al[4], rsum[4];
    #pragma unroll
    for (int i = 0; i < 4; ++i) {
      const float mnew = fmaxf(mrow[i], tmax[i]);
      al[i] = __expf(mrow[i] - mnew);
      mrow[i] = mnew;
      float rs = 0.f;
      #pragma unroll
      for (int j = 0; j < 4; ++j) { s[i][j] = __expf(s[i][j] - mnew); rs += s[i][j]; }
      rsum[i] = rs;
    }
    #pragma unroll
    for (int off = 1; off < 16; off <<= 1)
      #pragma unroll
      for (int i = 0; i < 4; ++i)
        rsum[i] += __shfl_xor(rsum[i], off);
    #pragma unroll
    for (int i = 0; i < 4; ++i) {
      lrow[i] = lrow[i] * al[i] + rsum[i];
      #pragma unroll
      for (int j = 0; j < 4; ++j) o[i][j] *= al[i];
    }

    // ---- stage P, then O += P V ----
    #pragma unroll
    for (int i = 0; i < 4; ++i)
      *(float4*)&Ps[ty * 4 + i][tx * 4] = make_float4(s[i][0], s[i][1], s[i][2], s[i][3]);
    __syncthreads();

    #pragma unroll
    for (int c0 = 0; c0 < 64; c0 += 4) {
      float pv[4][4], vv[4][4];
      #pragma unroll
      for (int i = 0; i < 4; ++i) {
        const float4 t4 = *(const float4*)&Ps[ty * 4 + i][c0];
        pv[i][0] = t4.x; pv[i][1] = t4.y; pv[i][2] = t4.z; pv[i][3] = t4.w;
      }
      #pragma unroll
      for (int l = 0; l < 4; ++l) {
        const float4 t4 = *(const float4*)&Vs[c0 + l][tx * 4];
        vv[l][0] = t4.x; vv[l][1] = t4.y; vv[l][2] = t4.z; vv[l][3] = t4.w;
      }
      #pragma unroll
      for (int i = 0; i < 4; ++i)
        #pragma unroll
        for (int j = 0; j < 4; ++j)
          o[i][j] += pv[i][0] * vv[0][j] + pv[i][1] * vv[1][j]
                   + pv[i][2] * vv[2][j] + pv[i][3] * vv[3][j];
    }
  }

  // ---- epilogue: O / l ----
  #pragma unroll
  for (int i = 0; i < 4; ++i) {
    const float inv = 1.f / lrow[i];
    const float4 v = make_float4(o[i][0] * inv, o[i][1] * inv, o[i][2] * inv, o[i][3] * inv);
    *(float4*)(O + base + (q0 + ty * 4 + i) * HD + tx * 4) = v;
  }
}

// ======================================================================
extern "C" void kernel_launch(void* const* d_in, const int* in_sizes, int n_in,
                              void* d_out, int out_size, void* d_ws, size_t ws_size,
                              hipStream_t stream) {
  const float* x  = (const float*)d_in[0];
  const float* wq = (const float*)d_in[1];
  const float* wk = (const float*)d_in[2];
  const float* wv = (const float*)d_in[3];
  const float* wo = (const float*)d_in[4];
  const float* fc = (const float*)d_in[5];
  // d_in[6] = causal_mask: not needed (causality computed in-kernel)
  float* out = (float*)d_out;

  float* ws = (float*)d_ws;
  float* Qb = ws;                 //  (B,H,T,hd) 4M floats
  float* Kb = ws + 4194304;
  float* Vb = ws + 8388608;
  float* AO = ws + 12582912;      // attention output, (B,H,T,hd)

  const int M = 2 * T_SEQ;        // 4096
  const int N = DMODEL;           // 1024
  const int K = DMODEL;           // 1024
  dim3 gg(N / 128, M / 128);      // (8, 32)

  hipLaunchKernelGGL((gemm_nt_kernel<0, 1>), gg, dim3(256), 0, stream, x, wq, Qb, M, N, K);
  hipLaunchKernelGGL((gemm_nt_kernel<0, 1>), gg, dim3(256), 0, stream, x, wk, Kb, M, N, K);
  hipLaunchKernelGGL((gemm_nt_kernel<0, 1>), gg, dim3(256), 0, stream, x, wv, Vb, M, N, K);

  const int rope_threads = 2 * NH * T_SEQ * 32;   // one per pair
  hipLaunchKernelGGL(rope_kernel, dim3(rope_threads / 256), dim3(256), 0, stream, Qb, Kb, fc);

  hipLaunchKernelGGL(attn_kernel, dim3(T_SEQ / 64, 2 * NH), dim3(256), 0, stream, Qb, Kb, Vb, AO);

  hipLaunchKernelGGL((gemm_nt_kernel<1, 0>), gg, dim3(256), 0, stream, AO, wo, out, M, N, K);
}

// Round 3
// 346.998 us; speedup vs baseline: 3.8014x; 3.8014x over previous
//
#include <hip/hip_runtime.h>
#include <hip/hip_bf16.h>

#define T_SEQ 2048
#define DMODEL 1024
#define NH 16
#define HD 64

typedef __attribute__((ext_vector_type(8))) short bf16x8;
typedef __attribute__((ext_vector_type(4))) float f32x4;

__device__ __forceinline__ f32x4 mfma16(bf16x8 a, bf16x8 b, f32x4 c) {
  return __builtin_amdgcn_mfma_f32_16x16x32_bf16(a, b, c, 0, 0, 0);
}

__device__ __forceinline__ unsigned short f2b(float f) {
  return __builtin_bit_cast(unsigned short, __float2bfloat16(f));
}
__device__ __forceinline__ float b2f(unsigned short u) {
  return __builtin_bit_cast(float, (unsigned)u << 16);
}

// ======================================================================
// fp32 -> bf16 conversion, 4 elems/thread
// ======================================================================
__global__ __launch_bounds__(256)
void cvt_kernel(const float* __restrict__ in, unsigned short* __restrict__ out, int n4) {
  const int i = blockIdx.x * 256 + threadIdx.x;
  if (i < n4) {
    const float4 v = ((const float4*)in)[i];
    ushort4 o;
    o.x = f2b(v.x); o.y = f2b(v.y); o.z = f2b(v.z); o.w = f2b(v.w);
    ((ushort4*)out)[i] = o;
  }
}

// ======================================================================
// bf16 GEMM: C[m,n] = sum_k A[m,k]*B[n,k].  BM=BN=128, BK=32, 256 thr,
// 4 waves each owning a 64x64 quadrant (4x4 fragments of 16x16x32 MFMA).
// LDS XOR-swizzled ([row][ (seg ^ (row&3))*16B ]) for conflict-free b128.
// AMODE 0: A row-major.  AMODE 1: A gathered from (B,H,T,hd) bf16.
// CMODE 0: C fp32 row-major (uses N).
// CMODE 3: fused QKV: n<2048 -> Q/K (B,H,T,hd) bf16 at Cq; n>=2048 -> V^T bf16 at Cv.
// ======================================================================
template<int AMODE, int CMODE>
__global__ __launch_bounds__(256)
void gemm_bf16(const unsigned short* __restrict__ A, const unsigned short* __restrict__ B,
               unsigned short* __restrict__ Cq, unsigned short* __restrict__ Cv,
               float* __restrict__ Cf, int M, int N, int K) {
  __shared__ __align__(16) unsigned short As[4096];  // 128 x 32 bf16, swizzled
  __shared__ __align__(16) unsigned short Bs[4096];
  const int tid  = threadIdx.x;
  const int wid  = tid >> 6, lane = tid & 63;
  const int lg   = lane >> 4, lr = lane & 15;
  const int wr   = wid >> 1, wc = wid & 1;
  const int m0   = blockIdx.y * 128, n0 = blockIdx.x * 128;

  f32x4 acc[4][4];
  const f32x4 z = {0.f, 0.f, 0.f, 0.f};
  #pragma unroll
  for (int i = 0; i < 4; ++i)
    #pragma unroll
    for (int j = 0; j < 4; ++j) acc[i][j] = z;

  for (int k0 = 0; k0 < K; k0 += 32) {
    // ---- reg-stage A,B tiles with XOR-swizzled ds_write ----
    #pragma unroll
    for (int it = 0; it < 2; ++it) {
      const int c = tid + it * 256;      // 512 chunks of 16B per tile
      const int r = c >> 2, j = c & 3;   // row 0..127, 16B-seg 0..3
      int ga;
      if (AMODE == 0) ga = (m0 + r) * K + k0 + j * 8;
      else {
        const int m = m0 + r, b = m >> 11, t = m & 2047;
        ga = ((b * NH + (k0 >> 6)) * T_SEQ + t) * HD + (k0 & 63) + j * 8;
      }
      const uint4 av = *(const uint4*)(A + ga);
      *(uint4*)((char*)As + r * 64 + ((j ^ (r & 3)) << 4)) = av;
      const int gb = (n0 + r) * K + k0 + j * 8;
      const uint4 bv = *(const uint4*)(B + gb);
      *(uint4*)((char*)Bs + r * 64 + ((j ^ (r & 3)) << 4)) = bv;
    }
    __syncthreads();

    bf16x8 af[4], bfr[4];
    #pragma unroll
    for (int f = 0; f < 4; ++f) {
      const int ra = wr * 64 + f * 16 + lr;
      af[f]  = *(const bf16x8*)((const char*)As + ra * 64 + ((lg ^ (ra & 3)) << 4));
      const int rb = wc * 64 + f * 16 + lr;
      bfr[f] = *(const bf16x8*)((const char*)Bs + rb * 64 + ((lg ^ (rb & 3)) << 4));
    }
    #pragma unroll
    for (int i = 0; i < 4; ++i)
      #pragma unroll
      for (int j = 0; j < 4; ++j)
        acc[i][j] = mfma16(af[i], bfr[j], acc[i][j]);
    __syncthreads();
  }

  // ---- epilogue.  C layout: col = lane&15, row = (lane>>4)*4 + reg ----
  #pragma unroll
  for (int i = 0; i < 4; ++i)
    #pragma unroll
    for (int j = 0; j < 4; ++j)
      #pragma unroll
      for (int reg = 0; reg < 4; ++reg) {
        const int m = m0 + wr * 64 + i * 16 + lg * 4 + reg;
        const int n = n0 + wc * 64 + j * 16 + lr;
        const float val = acc[i][j][reg];
        if (CMODE == 0) {
          Cf[m * N + n] = val;
        } else {
          const int b = m >> 11, t = m & 2047;
          if (n < 2048) {
            const int tensor = n >> 10, nq = n & 1023;
            const int head = nq >> 6, d = nq & 63;
            Cq[tensor * 4194304 + ((b * NH + head) * T_SEQ + t) * HD + d] = f2b(val);
          } else {
            const int nv = n - 2048, head = nv >> 6, d = nv & 63;
            Cv[((b * NH + head) * HD + d) * T_SEQ + t] = f2b(val);
          }
        }
      }
}

// ======================================================================
// RoPE in-place on bf16 Q,K in (B,H,T,hd).  One thread per (row, pair).
// ======================================================================
__global__ __launch_bounds__(256)
void rope_kernel(unsigned short* __restrict__ Q, unsigned short* __restrict__ Kp,
                 const float* __restrict__ fc) {
  const int idx = blockIdx.x * 256 + threadIdx.x;   // B*NH*T*32 threads
  const int i   = idx & 31;
  const int row = idx >> 5;
  const int t   = row & (T_SEQ - 1);
  const int a   = row * HD + 2 * i;
  const float c = fc[t * 64 + 2 * i];
  const float s = fc[t * 64 + 2 * i + 1];
  const unsigned uq = *(unsigned*)(Q + a);
  const unsigned uk = *(unsigned*)(Kp + a);
  const float q0 = b2f((unsigned short)uq), q1 = b2f((unsigned short)(uq >> 16));
  const float k0 = b2f((unsigned short)uk), k1 = b2f((unsigned short)(uk >> 16));
  const unsigned short qo0 = f2b(q0 * c - q1 * s), qo1 = f2b(q0 * s + q1 * c);
  const unsigned short ko0 = f2b(k0 * c - k1 * s), ko1 = f2b(k0 * s + k1 * c);
  *(unsigned*)(Q + a)  = (unsigned)qo0 | ((unsigned)qo1 << 16);
  *(unsigned*)(Kp + a) = (unsigned)ko0 | ((unsigned)ko1 << 16);
}

// ======================================================================
// MFMA flash attention.  Block = 4 waves x 16 q-rows = 64-row Q tile.
// K tiles of 64 keys.  Q: (B,H,T,hd) bf16.  K: (B,H,T,hd) bf16.
// V: V^T (B,H,hd,T) bf16.  Output AO: (B,H,T,hd) bf16.
// LDS: Ks[64 keys][128B swz] + Vs[64 d][128B swz] + Ps[4 waves][16 q][128B swz].
// ======================================================================
__global__ __launch_bounds__(256)
void attn_kernel(const unsigned short* __restrict__ Q, const unsigned short* __restrict__ K,
                 const unsigned short* __restrict__ V, unsigned short* __restrict__ AO) {
  __shared__ __align__(16) char Ks[8192];
  __shared__ __align__(16) char Vs[8192];
  __shared__ __align__(16) char Ps[8192];
  const int tid = threadIdx.x;
  const int wid = tid >> 6, lane = tid & 63;
  const int lg  = lane >> 4, lr = lane & 15;
  const int qt  = gridDim.x - 1 - blockIdx.x;     // heavy-first for causal balance
  const int bh  = blockIdx.y;
  const int base = bh * (T_SEQ * HD);             // elements
  const int q0  = qt * 64;
  char* Psw = Ps + wid * 2048;

  // Q fragments in registers: row = q0 + wid*16 + lr, d = db*32 + lg*8 .. +7
  bf16x8 qf[2];
  #pragma unroll
  for (int db = 0; db < 2; ++db)
    qf[db] = *(const bf16x8*)(Q + base + (q0 + wid * 16 + lr) * HD + db * 32 + lg * 8);

  f32x4 of[4];
  const f32x4 z = {0.f, 0.f, 0.f, 0.f};
  #pragma unroll
  for (int db = 0; db < 4; ++db) of[db] = z;
  float mrow[4], lrow[4];
  #pragma unroll
  for (int r = 0; r < 4; ++r) { mrow[r] = -3.0e38f; lrow[r] = 0.f; }

  for (int kt = 0; kt <= qt; ++kt) {
    const int k0 = kt * 64;
    __syncthreads();   // previous tile's reads done
    // ---- stage K (row=key, 128B) and V^T (row=d, 128B), XOR-swizzled ----
    #pragma unroll
    for (int it = 0; it < 2; ++it) {
      const int c = tid + it * 256;          // 512 chunks of 16B per tile
      const int r = c >> 3, sg = c & 7;
      const uint4 kv = *(const uint4*)(K + base + (k0 + r) * HD + sg * 8);
      *(uint4*)(Ks + r * 128 + ((sg ^ (r & 7)) << 4)) = kv;
      const uint4 vv = *(const uint4*)(V + base + r * T_SEQ + k0 + sg * 8);
      *(uint4*)(Vs + r * 128 + ((sg ^ (r & 7)) << 4)) = vv;
    }
    __syncthreads();

    // ---- S = Q K^T  (per wave: 16 q x 64 keys) ----
    f32x4 s[4];
    #pragma unroll
    for (int kb = 0; kb < 4; ++kb) {
      const int key = kb * 16 + lr;
      const bf16x8 kf0 = *(const bf16x8*)(Ks + key * 128 + ((lg       ^ (key & 7)) << 4));
      const bf16x8 kf1 = *(const bf16x8*)(Ks + key * 128 + (((4 + lg) ^ (key & 7)) << 4));
      s[kb] = mfma16(qf[0], kf0, z);
      s[kb] = mfma16(qf[1], kf1, s[kb]);
    }

    // ---- scale + causal mask ----
    #pragma unroll
    for (int kb = 0; kb < 4; ++kb)
      #pragma unroll
      for (int r = 0; r < 4; ++r) s[kb][r] *= 0.125f;
    if (kt == qt) {
      #pragma unroll
      for (int kb = 0; kb < 4; ++kb)
        #pragma unroll
        for (int r = 0; r < 4; ++r)
          if (kb * 16 + lr > wid * 16 + lg * 4 + r) s[kb][r] = -1.0e9f;
    }

    // ---- online softmax (rows live on 16 lanes sharing lane>>4) ----
    float tmax[4];
    #pragma unroll
    for (int r = 0; r < 4; ++r)
      tmax[r] = fmaxf(fmaxf(s[0][r], s[1][r]), fmaxf(s[2][r], s[3][r]));
    #pragma unroll
    for (int off = 1; off < 16; off <<= 1)
      #pragma unroll
      for (int r = 0; r < 4; ++r) tmax[r] = fmaxf(tmax[r], __shfl_xor(tmax[r], off));

    float al[4], rsum[4];
    #pragma unroll
    for (int r = 0; r < 4; ++r) {
      const float mnew = fmaxf(mrow[r], tmax[r]);
      al[r] = __expf(mrow[r] - mnew);
      mrow[r] = mnew;
      float rs = 0.f;
      #pragma unroll
      for (int kb = 0; kb < 4; ++kb) { s[kb][r] = __expf(s[kb][r] - mnew); rs += s[kb][r]; }
      rsum[r] = rs;
    }
    #pragma unroll
    for (int off = 1; off < 16; off <<= 1)
      #pragma unroll
      for (int r = 0; r < 4; ++r) rsum[r] += __shfl_xor(rsum[r], off);
    #pragma unroll
    for (int r = 0; r < 4; ++r) {
      lrow[r] = lrow[r] * al[r] + rsum[r];
      #pragma unroll
      for (int db = 0; db < 4; ++db) of[db][r] *= al[r];
    }

    // ---- P -> bf16 via per-wave LDS (re-fragment C-layout -> A-layout) ----
    #pragma unroll
    for (int kb = 0; kb < 4; ++kb)
      #pragma unroll
      for (int r = 0; r < 4; ++r) {
        const int q = lg * 4 + r;
        *(unsigned short*)(Psw + q * 128 + ((2 * (kb * 16 + lr)) ^ ((q & 7) << 4))) = f2b(s[kb][r]);
      }

    // ---- O += P V ----
    const bf16x8 pa0 = *(const bf16x8*)(Psw + lr * 128 + ((lg * 16)      ^ ((lr & 7) << 4)));
    const bf16x8 pa1 = *(const bf16x8*)(Psw + lr * 128 + ((64 + lg * 16) ^ ((lr & 7) << 4)));
    #pragma unroll
    for (int db = 0; db < 4; ++db) {
      const int vr = db * 16 + lr;
      const bf16x8 v0 = *(const bf16x8*)(Vs + vr * 128 + ((lg       ^ (vr & 7)) << 4));
      const bf16x8 v1 = *(const bf16x8*)(Vs + vr * 128 + (((4 + lg) ^ (vr & 7)) << 4));
      of[db] = mfma16(pa0, v0, of[db]);
      of[db] = mfma16(pa1, v1, of[db]);
    }
  }

  // ---- epilogue ----
  #pragma unroll
  for (int r = 0; r < 4; ++r) {
    const float inv = 1.f / lrow[r];
    #pragma unroll
    for (int db = 0; db < 4; ++db)
      AO[base + (q0 + wid * 16 + lg * 4 + r) * HD + db * 16 + lr] = f2b(of[db][r] * inv);
  }
}

// ======================================================================
extern "C" void kernel_launch(void* const* d_in, const int* in_sizes, int n_in,
                              void* d_out, int out_size, void* d_ws, size_t ws_size,
                              hipStream_t stream) {
  const float* x  = (const float*)d_in[0];
  const float* wq = (const float*)d_in[1];
  const float* wk = (const float*)d_in[2];
  const float* wv = (const float*)d_in[3];
  const float* wo = (const float*)d_in[4];
  const float* fc = (const float*)d_in[5];
  float* out = (float*)d_out;

  const int ME = 1 << 20;
  unsigned short* W    = (unsigned short*)d_ws;
  unsigned short* xb   = W;               // 4M  x bf16
  unsigned short* wqkv = W + 4 * ME;      // 3M  [wq;wk;wv] bf16
  unsigned short* wob  = W + 7 * ME;      // 1M
  unsigned short* Qb   = W + 8 * ME;      // 4M  (B,H,T,hd); Kb contiguous after
  unsigned short* Kb   = W + 12 * ME;
  unsigned short* Vt   = W + 16 * ME;     // 4M  (B,H,hd,T)
  unsigned short* AO   = W + 20 * ME;     // 4M  (B,H,T,hd)

  // ---- fp32 -> bf16 ----
  hipLaunchKernelGGL(cvt_kernel, dim3(4096), dim3(256), 0, stream, x, xb, ME);
  hipLaunchKernelGGL(cvt_kernel, dim3(1024), dim3(256), 0, stream, wq, wqkv,          ME / 4);
  hipLaunchKernelGGL(cvt_kernel, dim3(1024), dim3(256), 0, stream, wk, wqkv + ME,     ME / 4);
  hipLaunchKernelGGL(cvt_kernel, dim3(1024), dim3(256), 0, stream, wv, wqkv + 2 * ME, ME / 4);
  hipLaunchKernelGGL(cvt_kernel, dim3(1024), dim3(256), 0, stream, wo, wob,           ME / 4);

  // ---- fused QKV projection: (4096 x 3072) = xb @ [wq;wk;wv]^T ----
  hipLaunchKernelGGL((gemm_bf16<0, 3>), dim3(24, 32), dim3(256), 0, stream,
                     xb, wqkv, Qb, Vt, (float*)nullptr, 4096, 3072, 1024);

  // ---- RoPE on Q,K ----
  hipLaunchKernelGGL(rope_kernel, dim3(8192), dim3(256), 0, stream, Qb, Kb, fc);

  // ---- attention ----
  hipLaunchKernelGGL(attn_kernel, dim3(32, 32), dim3(256), 0, stream, Qb, Kb, Vt, AO);

  // ---- output projection ----
  hipLaunchKernelGGL((gemm_bf16<1, 0>), dim3(8, 32), dim3(256), 0, stream,
                     AO, wob, (unsigned short*)nullptr, (unsigned short*)nullptr,
                     out, 4096, 1024, 1024);
}

// Round 5
// 225.483 us; speedup vs baseline: 5.8500x; 1.5389x over previous
//
#include <hip/hip_runtime.h>
#include <hip/hip_bf16.h>

#define T_SEQ 2048
#define DMODEL 1024
#define NH 16
#define HD 64

typedef __attribute__((ext_vector_type(8))) short bf16x8;
typedef __attribute__((ext_vector_type(4))) float f32x4;
typedef __attribute__((ext_vector_type(16))) float f32x16;

__device__ __forceinline__ f32x4 mfma16(bf16x8 a, bf16x8 b, f32x4 c) {
  return __builtin_amdgcn_mfma_f32_16x16x32_bf16(a, b, c, 0, 0, 0);
}
__device__ __forceinline__ f32x16 mfma32(bf16x8 a, bf16x8 b, f32x16 c) {
  return __builtin_amdgcn_mfma_f32_32x32x16_bf16(a, b, c, 0, 0, 0);
}

__device__ __forceinline__ unsigned short f2b(float f) {
  return __builtin_bit_cast(unsigned short, __float2bfloat16(f));
}
__device__ __forceinline__ unsigned packpair(float lo, float hi) {
  return (unsigned)f2b(lo) | ((unsigned)f2b(hi) << 16);  // compiler fuses to v_cvt_pk_bf16_f32
}
__device__ __forceinline__ float b2f(unsigned short u) {
  return __builtin_bit_cast(float, (unsigned)u << 16);
}

// async global->LDS, 16B per lane; LDS dest = wave-uniform base + lane*16
#define GLOAD16(g, l)                                                          \
  __builtin_amdgcn_global_load_lds(                                            \
      (const __attribute__((address_space(1))) unsigned int*)(g),              \
      (__attribute__((address_space(3))) unsigned int*)(l), 16, 0, 0)

// swap: a.hi <-> b.lo  (after: a = [a.lo, b.lo_old], b = [a.hi_old, b.hi])
#define PLSWAP(a, b) asm("v_permlane32_swap_b32 %0, %1" : "+v"(a), "+v"(b))

// ======================================================================
// fused fp32->bf16 conversion for all 5 tensors (4 elems/thread)
// groups: [0,1M): x -> xb ; then 256K each: wq,wk,wv -> wqkv ; wo -> wob
// ======================================================================
__global__ __launch_bounds__(256)
void cvt_all(const float* __restrict__ x,  const float* __restrict__ wq,
             const float* __restrict__ wk, const float* __restrict__ wv,
             const float* __restrict__ wo, unsigned short* __restrict__ xb,
             unsigned short* __restrict__ wqkv, unsigned short* __restrict__ wob) {
  const int g = blockIdx.x * 256 + threadIdx.x;   // 0 .. 2M-1
  const int M1 = 1 << 20, WG = 1 << 18;
  const float* src; unsigned short* dst; int off;
  if (g < M1)               { src = x;  dst = xb;             off = g; }
  else if (g < M1 + WG)     { src = wq; dst = wqkv;           off = g - M1; }
  else if (g < M1 + 2 * WG) { src = wk; dst = wqkv + M1;      off = g - M1 - WG; }
  else if (g < M1 + 3 * WG) { src = wv; dst = wqkv + 2 * M1;  off = g - M1 - 2 * WG; }
  else                      { src = wo; dst = wob;            off = g - M1 - 3 * WG; }
  const float4 v = ((const float4*)src)[off];
  ushort4 o;
  o.x = f2b(v.x); o.y = f2b(v.y); o.z = f2b(v.z); o.w = f2b(v.w);
  ((ushort4*)dst)[off] = o;
}

// ======================================================================
// bf16 GEMM: C[m,n] = sum_k A[m,k]*B[n,k].  BM=BN=128, BK=32, 256 thr,
// 4 waves each owning a 64x64 quadrant (4x4 fragments of 16x16x32 MFMA).
// Staging: global_load_lds w=16, linear LDS dest, pre-swizzled source,
// XOR-swizzled read (slot = chunk ^ (row&3)) -> conflict-free b128.
// ======================================================================
template<int AMODE, int CMODE>
__global__ __launch_bounds__(256)
void gemm_bf16(const unsigned short* __restrict__ A, const unsigned short* __restrict__ B,
               unsigned short* __restrict__ Cq, unsigned short* __restrict__ Cv,
               float* __restrict__ Cf, int M, int N, int K) {
  __shared__ __align__(16) unsigned short As[4096];  // 128 x 32 bf16
  __shared__ __align__(16) unsigned short Bs[4096];
  const int tid  = threadIdx.x;
  const int wid  = tid >> 6, lane = tid & 63;
  const int lg   = lane >> 4, lr = lane & 15;
  const int wr   = wid >> 1, wc = wid & 1;
  const int m0   = blockIdx.y * 128, n0 = blockIdx.x * 128;

  f32x4 acc[4][4];
  const f32x4 z = {0.f, 0.f, 0.f, 0.f};
  #pragma unroll
  for (int i = 0; i < 4; ++i)
    #pragma unroll
    for (int j = 0; j < 4; ++j) acc[i][j] = z;

  for (int k0 = 0; k0 < K; k0 += 32) {
    __syncthreads();   // prior iteration's fragment reads done
    #pragma unroll
    for (int i = 0; i < 2; ++i) {
      const int c = i * 256 + wid * 64 + lane;   // linear 16B chunk 0..511
      const int r = c >> 2, slot = c & 3, js = slot ^ (r & 3);
      const unsigned short* ga;
      if (AMODE == 0) ga = A + (m0 + r) * K + k0 + js * 8;
      else {
        const int m = m0 + r;
        ga = A + (((m >> 11) * NH + (k0 >> 6)) * T_SEQ + (m & 2047)) * HD + (k0 & 63) + js * 8;
      }
      GLOAD16(ga, (char*)As + i * 4096 + wid * 1024);
      const unsigned short* gb = B + (n0 + r) * K + k0 + js * 8;
      GLOAD16(gb, (char*)Bs + i * 4096 + wid * 1024);
    }
    __syncthreads();   // compiler drains vmcnt before this barrier

    bf16x8 af[4], bfr[4];
    #pragma unroll
    for (int f = 0; f < 4; ++f) {
      const int ra = wr * 64 + f * 16 + lr;
      af[f]  = *(const bf16x8*)((const char*)As + ra * 64 + ((lg ^ (ra & 3)) << 4));
      const int rb = wc * 64 + f * 16 + lr;
      bfr[f] = *(const bf16x8*)((const char*)Bs + rb * 64 + ((lg ^ (rb & 3)) << 4));
    }
    #pragma unroll
    for (int i = 0; i < 4; ++i)
      #pragma unroll
      for (int j = 0; j < 4; ++j)
        acc[i][j] = mfma16(af[i], bfr[j], acc[i][j]);
  }

  // ---- epilogue.  C layout: col = lane&15, row = (lane>>4)*4 + reg ----
  #pragma unroll
  for (int i = 0; i < 4; ++i)
    #pragma unroll
    for (int j = 0; j < 4; ++j)
      #pragma unroll
      for (int reg = 0; reg < 4; ++reg) {
        const int m = m0 + wr * 64 + i * 16 + lg * 4 + reg;
        const int n = n0 + wc * 64 + j * 16 + lr;
        const float val = acc[i][j][reg];
        if (CMODE == 0) {
          Cf[m * N + n] = val;
        } else {
          const int b = m >> 11, t = m & 2047;
          if (n < 2048) {
            const int tensor = n >> 10, nq = n & 1023;
            const int head = nq >> 6, d = nq & 63;
            Cq[tensor * 4194304 + ((b * NH + head) * T_SEQ + t) * HD + d] = f2b(val);
          } else {
            const int nv = n - 2048, head = nv >> 6, d = nv & 63;
            Cv[((b * NH + head) * HD + d) * T_SEQ + t] = f2b(val);
          }
        }
      }
}

// ======================================================================
// RoPE in-place on bf16 Q,K in (B,H,T,hd).  Q additionally pre-scaled by
// 1/8 (= hd^-0.5, exact power of 2) so attention needs no scale multiply.
// ======================================================================
__global__ __launch_bounds__(256)
void rope_kernel(unsigned short* __restrict__ Q, unsigned short* __restrict__ Kp,
                 const float* __restrict__ fc) {
  const int idx = blockIdx.x * 256 + threadIdx.x;   // B*NH*T*32 threads
  const int i   = idx & 31;
  const int row = idx >> 5;
  const int t   = row & (T_SEQ - 1);
  const int a   = row * HD + 2 * i;
  const float c = fc[t * 64 + 2 * i];
  const float s = fc[t * 64 + 2 * i + 1];
  const unsigned uq = *(unsigned*)(Q + a);
  const unsigned uk = *(unsigned*)(Kp + a);
  const float q0 = b2f((unsigned short)uq), q1 = b2f((unsigned short)(uq >> 16));
  const float k0 = b2f((unsigned short)uk), k1 = b2f((unsigned short)(uk >> 16));
  const unsigned short qo0 = f2b((q0 * c - q1 * s) * 0.125f);
  const unsigned short qo1 = f2b((q0 * s + q1 * c) * 0.125f);
  const unsigned short ko0 = f2b(k0 * c - k1 * s);
  const unsigned short ko1 = f2b(k0 * s + k1 * c);
  *(unsigned*)(Q + a)  = (unsigned)qo0 | ((unsigned)qo1 << 16);
  *(unsigned*)(Kp + a) = (unsigned)ko0 | ((unsigned)ko1 << 16);
}

// ======================================================================
// Swapped-operand 32x32 MFMA flash attention.
// Block = 4 waves x 32 q-rows = 128 q.  KV tile = 64 keys.
// S^T = K Q^T  (A=K-frag from LDS, B=Q-frag from regs) -> lane owns one
// q-row's P (32 keys; partner lane l^32 holds the other 32).
// Softmax lane-local; P->A-frag in-register (cvt_pk + permlane32_swap).
// O^T = V^T P^T accumulated transposed -> per-q rescale lane-local.
// Q pre-scaled by 1/8.  Grid 512 = 8 XCD groups x 4 bh x 16 qb, heavy-first.
// ======================================================================
__global__ __launch_bounds__(256)
void attn_kernel(const unsigned short* __restrict__ Q, const unsigned short* __restrict__ K,
                 const unsigned short* __restrict__ V, unsigned short* __restrict__ AO) {
  __shared__ __align__(16) char Ks[8192];   // [key 0..63][128B: d-chunks swizzled]
  __shared__ __align__(16) char Vs[8192];   // [d 0..63][128B: key-chunks swizzled]
  const int tid = threadIdx.x;
  const int wid = tid >> 6, lane = tid & 63;
  const int l31 = lane & 31, hi = lane >> 5;

  // XCD-aware heavy-first mapping: each XCD owns 4 heads entirely.
  const int id  = blockIdx.x;          // 0..511
  const int xcd = id & 7, j = id >> 3;
  const int bh  = xcd * 4 + (j & 3);
  const int qb  = 15 - (j >> 2);       // heavy-first
  const int base = bh * (T_SEQ * HD);
  const int qw  = qb * 128 + wid * 32; // wave's first q row
  const int q   = qw + l31;            // this lane's q row

  // Q fragments (B-operand): qfr[ds] = Q[q][ds*16 + hi*8 .. +7]
  bf16x8 qfr[4];
  #pragma unroll
  for (int ds = 0; ds < 4; ++ds)
    qfr[ds] = *(const bf16x8*)(Q + base + q * HD + ds * 16 + hi * 8);

  f32x16 o[2];
  #pragma unroll
  for (int r = 0; r < 16; ++r) { o[0][r] = 0.f; o[1][r] = 0.f; }
  float m_run = -1e30f, l_run = 0.f;

  const int ntiles = 2 * qb + 2;
  for (int kt = 0; kt < ntiles; ++kt) {
    const int k0 = kt * 64;
    __syncthreads();   // prior tile's LDS reads done
    // ---- stage K tile (rows=key) and V^T tile (rows=d) via gload_lds ----
    #pragma unroll
    for (int i = 0; i < 2; ++i) {
      const int c = i * 256 + wid * 64 + lane;   // linear chunk 0..511
      const int r = c >> 3, sg = c & 7, js = sg ^ (r & 7);
      GLOAD16(K + base + (k0 + r) * HD + js * 8, Ks + i * 4096 + wid * 1024);
      GLOAD16(V + base + r * T_SEQ + k0 + js * 8, Vs + i * 4096 + wid * 1024);
    }
    __syncthreads();   // vmcnt drained by compiler before barrier

    if (k0 <= qw + 31) {   // wave-uniform: any unmasked work in this tile?
      // ---- S^T = K Q^T : two 32-key blocks ----
      f32x16 s0, s1;
      #pragma unroll
      for (int r = 0; r < 16; ++r) { s0[r] = 0.f; s1[r] = 0.f; }
      #pragma unroll
      for (int ds = 0; ds < 4; ++ds) {
        const int sg = ds * 2 + hi;
        const int key0 = l31, key1 = 32 + l31;
        const bf16x8 kf0 = *(const bf16x8*)(Ks + key0 * 128 + ((sg ^ (key0 & 7)) << 4));
        const bf16x8 kf1 = *(const bf16x8*)(Ks + key1 * 128 + ((sg ^ (key1 & 7)) << 4));
        s0 = mfma32(kf0, qfr[ds], s0);
        s1 = mfma32(kf1, qfr[ds], s1);
      }

      // ---- causal mask (exactly one diagonal tile per wave) ----
      if (k0 + 63 > qw) {
        #pragma unroll
        for (int r = 0; r < 16; ++r) {
          const int kr = (r & 3) + 8 * (r >> 2) + 4 * hi;
          if (k0 + kr > q)      s0[r] = -1e30f;
          if (k0 + 32 + kr > q) s1[r] = -1e30f;
        }
      }

      // ---- lane-local online softmax ----
      float mx = s0[0];
      #pragma unroll
      for (int r = 1; r < 16; ++r) mx = fmaxf(mx, s0[r]);
      #pragma unroll
      for (int r = 0; r < 16; ++r) mx = fmaxf(mx, s1[r]);
      mx = fmaxf(mx, __shfl_xor(mx, 32));
      const float mnew = fmaxf(m_run, mx);
      const float alpha = __expf(m_run - mnew);
      m_run = mnew;
      float sumA = 0.f, sumB = 0.f;
      #pragma unroll
      for (int r = 0; r < 16; ++r) {
        s0[r] = __expf(s0[r] - mnew); sumA += s0[r];
        s1[r] = __expf(s1[r] - mnew); sumB += s1[r];
      }
      float sum = sumA + sumB;
      sum += __shfl_xor(sum, 32);
      l_run = l_run * alpha + sum;
      #pragma unroll
      for (int r = 0; r < 16; ++r) { o[0][r] *= alpha; o[1][r] *= alpha; }

      // ---- P -> bf16 A/B-frag in-register, then O^T += V^T P^T ----
      #pragma unroll
      for (int ks = 0; ks < 4; ++ks) {
        const f32x16 pt = (ks < 2) ? s0 : s1;
        const int m = 8 * (ks & 1);
        unsigned wA = packpair(pt[m + 0], pt[m + 1]);
        unsigned wB = packpair(pt[m + 2], pt[m + 3]);
        unsigned wC = packpair(pt[m + 4], pt[m + 5]);
        unsigned wD = packpair(pt[m + 6], pt[m + 7]);
        PLSWAP(wA, wC);   // -> wA = W0 (all lanes), wC = W2
        PLSWAP(wB, wD);   // -> wB = W1,            wD = W3
        uint4 uw; uw.x = wA; uw.y = wB; uw.z = wC; uw.w = wD;
        const bf16x8 pf = __builtin_bit_cast(bf16x8, uw);
        #pragma unroll
        for (int db = 0; db < 2; ++db) {
          const int d = db * 32 + l31;
          const int sg = ks * 2 + hi;
          const bf16x8 vf = *(const bf16x8*)(Vs + d * 128 + ((sg ^ (d & 7)) << 4));
          o[db] = mfma32(vf, pf, o[db]);
        }
      }
    }
  }

  // ---- epilogue: O^T/l -> AO (B,H,T,hd) ----
  const float inv = 1.f / l_run;
  #pragma unroll
  for (int db = 0; db < 2; ++db)
    #pragma unroll
    for (int t = 0; t < 4; ++t) {
      ushort4 pk;
      pk.x = f2b(o[db][4 * t + 0] * inv);
      pk.y = f2b(o[db][4 * t + 1] * inv);
      pk.z = f2b(o[db][4 * t + 2] * inv);
      pk.w = f2b(o[db][4 * t + 3] * inv);
      const int d = db * 32 + 8 * t + 4 * hi;
      *(ushort4*)(AO + base + q * HD + d) = pk;
    }
}

// ======================================================================
extern "C" void kernel_launch(void* const* d_in, const int* in_sizes, int n_in,
                              void* d_out, int out_size, void* d_ws, size_t ws_size,
                              hipStream_t stream) {
  const float* x  = (const float*)d_in[0];
  const float* wq = (const float*)d_in[1];
  const float* wk = (const float*)d_in[2];
  const float* wv = (const float*)d_in[3];
  const float* wo = (const float*)d_in[4];
  const float* fc = (const float*)d_in[5];
  float* out = (float*)d_out;

  const int ME = 1 << 20;
  unsigned short* W    = (unsigned short*)d_ws;
  unsigned short* xb   = W;               // 4M  x bf16
  unsigned short* wqkv = W + 4 * ME;      // 3M  [wq;wk;wv] bf16
  unsigned short* wob  = W + 7 * ME;      // 1M
  unsigned short* Qb   = W + 8 * ME;      // 4M  (B,H,T,hd); Kb contiguous after
  unsigned short* Kb   = W + 12 * ME;
  unsigned short* Vt   = W + 16 * ME;     // 4M  (B,H,hd,T)
  unsigned short* AO   = W + 20 * ME;     // 4M  (B,H,T,hd)

  // ---- fp32 -> bf16 (single fused kernel) ----
  hipLaunchKernelGGL(cvt_all, dim3(8192), dim3(256), 0, stream,
                     x, wq, wk, wv, wo, xb, wqkv, wob);

  // ---- fused QKV projection: (4096 x 3072) = xb @ [wq;wk;wv]^T ----
  hipLaunchKernelGGL((gemm_bf16<0, 3>), dim3(24, 32), dim3(256), 0, stream,
                     xb, wqkv, Qb, Vt, (float*)nullptr, 4096, 3072, 1024);

  // ---- RoPE on Q,K (Q pre-scaled by 1/8) ----
  hipLaunchKernelGGL(rope_kernel, dim3(8192), dim3(256), 0, stream, Qb, Kb, fc);

  // ---- attention ----
  hipLaunchKernelGGL(attn_kernel, dim3(512), dim3(256), 0, stream, Qb, Kb, Vt, AO);

  // ---- output projection ----
  hipLaunchKernelGGL((gemm_bf16<1, 0>), dim3(8, 32), dim3(256), 0, stream,
                     AO, wob, (unsigned short*)nullptr, (unsigned short*)nullptr,
                     out, 4096, 1024, 1024);
}